// Round 10
// baseline (207.795 us; speedup 1.0000x reference)
//
#include <hip/hip_runtime.h>
#include <hip/hip_cooperative_groups.h>
#include <math.h>

namespace cg = cooperative_groups;

#define FMPX 40
#define NPOS 1600          // 40*40
#define NCLS 80
#define NBOX 8000
#define KDIM 512
#define CAP  256           // per-class candidate capacity

// anchor (w,h) pairs
__constant__ float c_aw[5] = {17.f, 55.f, 92.f, 202.f, 289.f};
__constant__ float c_ah[5] = {25.f, 75.f, 206.f, 21.f, 311.f};

__device__ __forceinline__ float sigf(float x) { return 1.0f / (1.0f + expf(-x)); }

// ---------------------------------------------------------------------------
// K1: the three 1x1-conv GEMMs. BYTE-IDENTICAL to the R5-verified kernel
// (42.4 us, VALUBusy 40%). R12 lesson: 2-pos blocking regressed (grid 675->
// 351 halved occupancy, exposing A-prefetch vmcnt). R3: A+W both in LDS ->
// LDS-pipe-bound. R4: per-step s_load W worse. FMA order strictly sequential
// ascending k — bitwise-identical across rounds (absmax 2.0 stable).
// ---------------------------------------------------------------------------
__global__ __launch_bounds__(256) void k_gemm(
    const float* __restrict__ cls_feat, const float* __restrict__ reg_feat,
    const float* __restrict__ w_obj, const float* __restrict__ b_obj,
    const float* __restrict__ w_cls, const float* __restrict__ b_cls,
    const float* __restrict__ w_reg, const float* __restrict__ b_reg,
    float* __restrict__ clsRaw,   // [1600][400]
    float* __restrict__ roRaw)    // [1600][25]: 0..4 obj, 5..24 reg
{
    __shared__ float Ws[16 * KDIM];        // 32 KB
    const int mTile = blockIdx.x;          // 0..24
    const int nTile = blockIdx.y;          // 0..26
    const int hw0   = mTile * 64;
    const bool isCls = (nTile < 25);
    const float* feat = isCls ? cls_feat : reg_feat;

    const int pos = threadIdx.x & 63;
    const int og  = threadIdx.x >> 6;      // 0..3 (wave-uniform by construction)

    const float* ap = feat + hw0 + pos;

    float A0[8], A1[8];
#pragma unroll
    for (int t = 0; t < 8; t++) A0[t] = ap[t * NPOS];
#pragma unroll
    for (int t = 0; t < 8; t++) A1[t] = ap[(8 + t) * NPOS];

    for (int i = threadIdx.x * 4; i < 16 * KDIM; i += 256 * 4) {
        int r = i >> 9, k = i & 511;
        const float* src;
        bool valid = true;
        if (isCls) {
            src = w_cls + (nTile * 16 + r) * KDIM + k;
        } else {
            int o = (nTile - 25) * 16 + r;
            if (o < 5)       src = w_obj + o * KDIM + k;
            else if (o < 25) src = w_reg + (o - 5) * KDIM + k;
            else           { src = w_obj; valid = false; }
        }
        float4 v = valid ? *(const float4*)src : make_float4(0.f, 0.f, 0.f, 0.f);
        *(float4*)&Ws[i] = v;
    }

    float bias[4];
    bool ok[4];
#pragma unroll
    for (int j = 0; j < 4; j++) {
        int r = og * 4 + j;
        if (isCls) {
            bias[j] = b_cls[nTile * 16 + r]; ok[j] = true;
        } else {
            int o = (nTile - 25) * 16 + r;
            if (o < 5)       { bias[j] = b_obj[o];     ok[j] = true; }
            else if (o < 25) { bias[j] = b_reg[o - 5]; ok[j] = true; }
            else             { bias[j] = 0.0f;         ok[j] = false; }
        }
    }

    __syncthreads();   // Ws ready; only barrier in the kernel

    float acc[4] = {0.f, 0.f, 0.f, 0.f};
    const float* wsBase = &Ws[(og * 4) * KDIM];

    for (int kk = 0; kk < KDIM - 16; kk += 16) {
#pragma unroll
        for (int j = 0; j < 4; j++) {
            const float* wp = wsBase + j * KDIM + kk;
            acc[j] += A0[0] * wp[0]; acc[j] += A0[1] * wp[1];
            acc[j] += A0[2] * wp[2]; acc[j] += A0[3] * wp[3];
            acc[j] += A0[4] * wp[4]; acc[j] += A0[5] * wp[5];
            acc[j] += A0[6] * wp[6]; acc[j] += A0[7] * wp[7];
        }
#pragma unroll
        for (int t = 0; t < 8; t++) A0[t] = ap[(kk + 16 + t) * NPOS];
#pragma unroll
        for (int j = 0; j < 4; j++) {
            const float* wp = wsBase + j * KDIM + kk + 8;
            acc[j] += A1[0] * wp[0]; acc[j] += A1[1] * wp[1];
            acc[j] += A1[2] * wp[2]; acc[j] += A1[3] * wp[3];
            acc[j] += A1[4] * wp[4]; acc[j] += A1[5] * wp[5];
            acc[j] += A1[6] * wp[6]; acc[j] += A1[7] * wp[7];
        }
#pragma unroll
        for (int t = 0; t < 8; t++) A1[t] = ap[(kk + 24 + t) * NPOS];
    }
    {
        const int kk = KDIM - 16;
#pragma unroll
        for (int j = 0; j < 4; j++) {
            const float* wp = wsBase + j * KDIM + kk;
            acc[j] += A0[0] * wp[0]; acc[j] += A0[1] * wp[1];
            acc[j] += A0[2] * wp[2]; acc[j] += A0[3] * wp[3];
            acc[j] += A0[4] * wp[4]; acc[j] += A0[5] * wp[5];
            acc[j] += A0[6] * wp[6]; acc[j] += A0[7] * wp[7];
        }
#pragma unroll
        for (int j = 0; j < 4; j++) {
            const float* wp = wsBase + j * KDIM + kk + 8;
            acc[j] += A1[0] * wp[0]; acc[j] += A1[1] * wp[1];
            acc[j] += A1[2] * wp[2]; acc[j] += A1[3] * wp[3];
            acc[j] += A1[4] * wp[4]; acc[j] += A1[5] * wp[5];
            acc[j] += A1[6] * wp[6]; acc[j] += A1[7] * wp[7];
        }
    }

    const int hw = hw0 + pos;
    if (isCls) {
        float4 rv = make_float4(acc[0] + bias[0], acc[1] + bias[1],
                                acc[2] + bias[2], acc[3] + bias[3]);
        *(float4*)&clsRaw[hw * 400 + nTile * 16 + og * 4] = rv;
    } else {
#pragma unroll
        for (int j = 0; j < 4; j++) {
            int o = (nTile - 25) * 16 + og * 4 + j;
            if (ok[j]) roRaw[hw * 25 + o] = acc[j] + bias[j];
        }
    }
}

// ---------------------------------------------------------------------------
// Per-box score/argmax/decode body — verbatim R5 k_box inner logic for box n.
// Factored so the fused kernel and the fallback k_box share IDENTICAL code
// (bitwise-identical outputs).
// ---------------------------------------------------------------------------
__device__ __forceinline__ void box_body(
    int n, int lane,
    const float* __restrict__ clsRaw, const float* __restrict__ roRaw,
    float* __restrict__ out, float4* __restrict__ nmsBox,
    float* __restrict__ nmsArea, float2* __restrict__ sl)
{
    const int hw = n / 5, a = n % 5;

    const float sobj = sigf(roRaw[hw * 25 + a]);
    const float* cbase = clsRaw + hw * 400 + a * 80;

    const int l4 = (lane < 20) ? lane : 19;     // clamp for safe address
    float4 cs = *(const float4*)(cbase + l4 * 4);

    float s0 = sqrtf(sobj * sigf(cs.x));
    float s1 = sqrtf(sobj * sigf(cs.y));
    float s2 = sqrtf(sobj * sigf(cs.z));
    float s3 = sqrtf(sobj * sigf(cs.w));
    float v = s0; int bi = l4 * 4;
    if (s1 > v) { v = s1; bi = l4 * 4 + 1; }
    if (s2 > v) { v = s2; bi = l4 * 4 + 2; }
    if (s3 > v) { v = s3; bi = l4 * 4 + 3; }
    if (lane >= 20) { v = -1.0f; bi = 0x7FFFFFFF; }  // scores are always > 0

#pragma unroll
    for (int off = 32; off >= 1; off >>= 1) {
        float ov = __shfl_xor(v, off);
        int   oi = __shfl_xor(bi, off);
        if (ov > v || (ov == v && oi < bi)) { v = ov; bi = oi; }
    }

    if (lane == 0) {
        const float* rp = roRaw + hw * 25 + 5 + a * 4;
        float r0 = rp[0], r1 = rp[1], r2 = rp[2], r3 = rp[3];
        float gx = (float)(hw % FMPX), gy = (float)(hw / FMPX);
        float cx = (sigf(r0) + gx) * 32.0f;
        float cy = (sigf(r1) + gy) * 32.0f;
        float wv = expf(r2) * c_aw[a];
        float hv = expf(r3) * c_ah[a];
        float x1 = cx - wv * 0.5f, y1 = cy - hv * 0.5f;
        float x2 = cx + wv * 0.5f, y2 = cy + hv * 0.5f;

        out[n * 4 + 0] = x1; out[n * 4 + 1] = y1;
        out[n * 4 + 2] = x2; out[n * 4 + 3] = y2;
        out[32000 + n] = v;
        out[40000 + n] = (float)bi;
        out[48000 + n] = 0.0f;            // keep init (nms phase sets 1s later)
        sl[n] = make_float2(v, (float)bi);

        // b2: reinterpret x1y1x2y2 as cxcywh (faithful to the reference nms())
        float nx1 = x1 - x2 * 0.5f, ny1 = y1 - y2 * 0.5f;
        float nx2 = x1 + x2 * 0.5f, ny2 = y1 + y2 * 0.5f;
        nmsBox[n]  = make_float4(nx1, ny1, nx2, ny2);
        nmsArea[n] = (nx2 - nx1) * (ny2 - ny1);
    }
}

// ---------------------------------------------------------------------------
// Per-class NMS body — VERBATIM the R5-verified k_nms (fastest measured k_nms,
// 41.2 us; R7-R13 redesigns all lost to it: the 4-wave barrier-interleaved
// bitonic+greedy hides LDS latency via TLP better than single-wave chains).
// ---------------------------------------------------------------------------
__device__ __forceinline__ void nms_body(
    int c,
    const float2* __restrict__ sl,
    const float4* __restrict__ nmsBox, const float* __restrict__ nmsArea,
    float* __restrict__ keepOut,
    float* ss, int* si, float* bx1, float* by1, float* bx2, float* by2,
    float* bar, int* supp, int* cntp)
{
    if (threadIdx.x == 0) *cntp = 0;
    __syncthreads();

    for (int i = threadIdx.x; i < NBOX; i += 256) {
        float2 p = sl[i];
        if (p.x >= 0.3f && (int)p.y == c) {
            int q = atomicAdd(cntp, 1);          // LDS atomic
            if (q < CAP) { ss[q] = p.x; si[q] = i; }
        }
    }
    __syncthreads();

    int m = *cntp;
    if (m > CAP) m = CAP;

    // P = next pow2 >= m (min 2); pad with -inf sentinels.
    int P = 2;
    while (P < m) P <<= 1;
    for (int i = threadIdx.x; i < P; i += 256) {
        if (i >= m) { ss[i] = -INFINITY; si[i] = 0x7FFFFFFF; }
    }
    __syncthreads();

    for (int size = 2; size <= P; size <<= 1) {
        for (int stride = size >> 1; stride > 0; stride >>= 1) {
            for (int t = threadIdx.x; t < P / 2; t += 256) {
                int lo = 2 * stride * (t / stride) + (t % stride);
                int hi = lo + stride;
                bool desc = ((lo & size) == 0);
                float slo = ss[lo], shi = ss[hi];
                int   ilo = si[lo], ihi = si[hi];
                bool loBetter = (slo > shi) || (slo == shi && ilo < ihi);
                bool doSwap = desc ? !loBetter : loBetter;
                if (doSwap) { ss[lo] = shi; ss[hi] = slo; si[lo] = ihi; si[hi] = ilo; }
            }
            __syncthreads();
        }
    }

    for (int i = threadIdx.x; i < m; i += 256) {
        int n = si[i];
        float4 b = nmsBox[n];
        bx1[i] = b.x; by1[i] = b.y; bx2[i] = b.z; by2[i] = b.w;
        bar[i] = nmsArea[n];
        supp[i] = 0;
    }
    __syncthreads();

    for (int k = 0; k < m; k++) {
        if (!supp[k]) {
            float kx1 = bx1[k], ky1 = by1[k], kx2 = bx2[k], ky2 = by2[k], ka = bar[k];
            for (int j = k + 1 + threadIdx.x; j < m; j += 256) {
                float xx1 = fmaxf(kx1, bx1[j]);
                float yy1 = fmaxf(ky1, by1[j]);
                float xx2 = fminf(kx2, bx2[j]);
                float yy2 = fminf(ky2, by2[j]);
                float inter = fmaxf(1e-10f, xx2 - xx1) * fmaxf(1e-10f, yy2 - yy1);
                float iou = inter / ((ka + bar[j] - inter) + 1e-14f);
                if (iou > 0.5f) supp[j] = 1;
            }
        }
        __syncthreads();
    }

    for (int j = threadIdx.x; j < m; j += 256) {
        if (!supp[j]) keepOut[si[j]] = 1.0f;
    }
}

// ---------------------------------------------------------------------------
// K2 (R14): cooperative fused box+nms. 160 blocks x 256 threads.
// Phase A: each block runs the verbatim box body for boxes b*50..b*50+49
// (one box per wave per trip). grid.sync() (device-scope fence -> cross-XCD
// visibility). Phase B: blocks 0..79 run the verbatim R5 nms body (c = b);
// blocks 80..159 exit after the sync (no further coordination needed).
// Eliminates one dispatch + one inter-kernel gap — the first direct probe of
// the invariant ~66 us residual (total - gemm - nms across all rounds).
// ---------------------------------------------------------------------------
__global__ __launch_bounds__(256) void k_boxnms(
    const float* __restrict__ clsRaw, const float* __restrict__ roRaw,
    float* __restrict__ out, float4* __restrict__ nmsBox,
    float* __restrict__ nmsArea, float2* __restrict__ sl)
{
    __shared__ float ss[CAP];
    __shared__ int   si[CAP];
    __shared__ float bx1[CAP], by1[CAP], bx2[CAP], by2[CAP], bar[CAP];
    __shared__ int   supp[CAP];
    __shared__ int   cnt;

    const int b    = blockIdx.x;           // 0..159
    const int lane = threadIdx.x & 63;
    const int wv   = threadIdx.x >> 6;

    // ---- phase A: 50 boxes per block, one per wave per trip ----
    for (int q = wv; q < 50; q += 4)
        box_body(b * 50 + q, lane, clsRaw, roRaw, out, nmsBox, nmsArea, sl);

    cg::this_grid().sync();                // all 8000 boxes visible device-wide

    // ---- phase B: per-class NMS on blocks 0..79 ----
    if (b < NCLS)
        nms_body(b, sl, nmsBox, nmsArea, out + 48000,
                 ss, si, bx1, by1, bx2, by2, bar, supp, &cnt);
}

// ---------------------------------------------------------------------------
// Fallback standalone kernels (verbatim R5 structure) — launched only if the
// cooperative launch is rejected at runtime; worst case == proven R5 baseline.
// ---------------------------------------------------------------------------
__global__ __launch_bounds__(256) void k_box(
    const float* __restrict__ clsRaw, const float* __restrict__ roRaw,
    float* __restrict__ out, float4* __restrict__ nmsBox,
    float* __restrict__ nmsArea, float2* __restrict__ sl)
{
    const int n = blockIdx.x * 4 + (threadIdx.x >> 6);
    box_body(n, threadIdx.x & 63, clsRaw, roRaw, out, nmsBox, nmsArea, sl);
}

__global__ __launch_bounds__(256) void k_nms(
    const float2* __restrict__ sl,
    const float4* __restrict__ nmsBox, const float* __restrict__ nmsArea,
    float* __restrict__ keepOut)
{
    __shared__ float ss[CAP];
    __shared__ int   si[CAP];
    __shared__ float bx1[CAP], by1[CAP], bx2[CAP], by2[CAP], bar[CAP];
    __shared__ int   supp[CAP];
    __shared__ int   cnt;
    nms_body(blockIdx.x, sl, nmsBox, nmsArea, keepOut,
             ss, si, bx1, by1, bx2, by2, bar, supp, &cnt);
}

// ---------------------------------------------------------------------------
extern "C" void kernel_launch(void* const* d_in, const int* in_sizes, int n_in,
                              void* d_out, int out_size, void* d_ws, size_t ws_size,
                              hipStream_t stream) {
    const float* cls_feat = (const float*)d_in[0];
    const float* reg_feat = (const float*)d_in[1];
    const float* w_obj    = (const float*)d_in[2];
    const float* b_obj    = (const float*)d_in[3];
    const float* w_cls    = (const float*)d_in[4];
    const float* b_cls    = (const float*)d_in[5];
    const float* w_reg    = (const float*)d_in[6];
    const float* b_reg    = (const float*)d_in[7];

    float* out = (float*)d_out;
    float* ws  = (float*)d_ws;

    // workspace layout (floats) — IDENTICAL to the R5-proven layout, 2.944 MB
    float*  clsRaw    = ws;                       // 640000
    float*  roRaw     = ws + 640000;              // 40000
    float4* nmsBox    = (float4*)(ws + 680000);   // 32000 floats (16B-aligned offset)
    float*  nmsArea   = ws + 712000;              // 8000
    float2* sl        = (float2*)(ws + 720000);   // 16000 floats (8B-aligned)
    // total 736000 floats

    k_gemm<<<dim3(25, 27), 256, 0, stream>>>(cls_feat, reg_feat,
                                             w_obj, b_obj, w_cls, b_cls, w_reg, b_reg,
                                             clsRaw, roRaw);

    void* args[6] = { (void*)&clsRaw, (void*)&roRaw, (void*)&out,
                      (void*)&nmsBox, (void*)&nmsArea, (void*)&sl };
    hipError_t err = hipLaunchCooperativeKernel((const void*)k_boxnms,
                                                dim3(160), dim3(256),
                                                args, 0, stream);
    if (err != hipSuccess) {
        // proven R5 path
        k_box<<<NBOX / 4, 256, 0, stream>>>(clsRaw, roRaw, out, nmsBox, nmsArea, sl);
        k_nms<<<NCLS, 256, 0, stream>>>(sl, nmsBox, nmsArea, out + 48000);
    }
}

// Round 11
// 152.889 us; speedup vs baseline: 1.3591x; 1.3591x over previous
//
#include <hip/hip_runtime.h>
#include <math.h>

#define FMPX 40
#define NPOS 1600          // 40*40
#define NCLS 80
#define NBOX 8000
#define KDIM 512
#define CAP  256           // per-class candidate capacity

// anchor (w,h) pairs
__constant__ float c_aw[5] = {17.f, 55.f, 92.f, 202.f, 289.f};
__constant__ float c_ah[5] = {25.f, 75.f, 206.f, 21.f, 311.f};

__device__ __forceinline__ float sigf(float x) { return 1.0f / (1.0f + expf(-x)); }

// ---------------------------------------------------------------------------
// K1 (R15): occupancy-retiled GEMM. R5 counters: 42.4 us, VALUBusy 40%,
// Occupancy 19.9% — grid 675 blocks = 1.6 waves/SIMD, latency-hiding-starved
// (FMA floor ~4.5 us, LDS floor ~10 us). R12 lesson: shrinking the grid made
// it worse; fix is the opposite — split N-tile 16 -> 8 outs: grid 25x54 =
// 1350 blocks (5.3 blocks/CU; LDS limit 10 at the 16KB W tile). Per-thread
// work halves (acc[2]); aggregate W-staging bytes IDENTICAL (1350x16KB ==
// 675x32KB); A-side L2 traffic doubles (~170MB, ~5us of L2 BW — negligible).
// og = tid>>6 wave-uniform, rows og*2(+1); same A/W values, same strictly-
// ascending-k FMA order per output -> bitwise-identical results.
// ---------------------------------------------------------------------------
__global__ __launch_bounds__(256) void k_gemm(
    const float* __restrict__ cls_feat, const float* __restrict__ reg_feat,
    const float* __restrict__ w_obj, const float* __restrict__ b_obj,
    const float* __restrict__ w_cls, const float* __restrict__ b_cls,
    const float* __restrict__ w_reg, const float* __restrict__ b_reg,
    float* __restrict__ clsRaw,   // [1600][400]
    float* __restrict__ roRaw)    // [1600][25]: 0..4 obj, 5..24 reg
{
    __shared__ float Ws[8 * KDIM];         // 16 KB
    const int mTile = blockIdx.x;          // 0..24  (64 positions)
    const int nTile = blockIdx.y;          // 0..53  (8 outs)
    const int hw0   = mTile * 64;
    const bool isCls = (nTile < 50);
    const float* feat = isCls ? cls_feat : reg_feat;

    const int pos = threadIdx.x & 63;
    const int og  = threadIdx.x >> 6;      // 0..3 (wave-uniform); rows og*2, og*2+1

    const float* ap = feat + hw0 + pos;

    // Initial A prefetch (k=0..15) — independent of W staging, issue early.
    float A0[8], A1[8];
#pragma unroll
    for (int t = 0; t < 8; t++) A0[t] = ap[t * NPOS];
#pragma unroll
    for (int t = 0; t < 8; t++) A1[t] = ap[(8 + t) * NPOS];

    // ---- stage W tile [8][512] (coalesced float4; 4 iters/thread) ----
    for (int i = threadIdx.x * 4; i < 8 * KDIM; i += 256 * 4) {
        int r = i >> 9, k = i & 511;
        const float* src;
        bool valid = true;
        if (isCls) {
            src = w_cls + (nTile * 8 + r) * KDIM + k;
        } else {
            int o = (nTile - 50) * 8 + r;    // 0..31
            if (o < 5)       src = w_obj + o * KDIM + k;
            else if (o < 25) src = w_reg + (o - 5) * KDIM + k;
            else           { src = w_obj; valid = false; }
        }
        float4 v = valid ? *(const float4*)src : make_float4(0.f, 0.f, 0.f, 0.f);
        *(float4*)&Ws[i] = v;
    }

    // ---- per-thread output metadata (wave-uniform) ----
    float bias[2];
    bool ok[2];
#pragma unroll
    for (int j = 0; j < 2; j++) {
        int r = og * 2 + j;                // row within the 8-wide tile
        if (isCls) {
            bias[j] = b_cls[nTile * 8 + r]; ok[j] = true;
        } else {
            int o = (nTile - 50) * 8 + r;
            if (o < 5)       { bias[j] = b_obj[o];     ok[j] = true; }
            else if (o < 25) { bias[j] = b_reg[o - 5]; ok[j] = true; }
            else             { bias[j] = 0.0f;         ok[j] = false; }
        }
    }

    __syncthreads();   // Ws ready; only barrier in the kernel

    float acc[2] = {0.f, 0.f};
    const float* wsBase = &Ws[(og * 2) * KDIM];

    // Main loop: pairs of 8-k steps; prefetch 16 k ahead. kk = 0..480.
    for (int kk = 0; kk < KDIM - 16; kk += 16) {
#pragma unroll
        for (int j = 0; j < 2; j++) {
            const float* wp = wsBase + j * KDIM + kk;    // LDS b128 x2, broadcast
            acc[j] += A0[0] * wp[0]; acc[j] += A0[1] * wp[1];
            acc[j] += A0[2] * wp[2]; acc[j] += A0[3] * wp[3];
            acc[j] += A0[4] * wp[4]; acc[j] += A0[5] * wp[5];
            acc[j] += A0[6] * wp[6]; acc[j] += A0[7] * wp[7];
        }
#pragma unroll
        for (int t = 0; t < 8; t++) A0[t] = ap[(kk + 16 + t) * NPOS];
#pragma unroll
        for (int j = 0; j < 2; j++) {
            const float* wp = wsBase + j * KDIM + kk + 8;
            acc[j] += A1[0] * wp[0]; acc[j] += A1[1] * wp[1];
            acc[j] += A1[2] * wp[2]; acc[j] += A1[3] * wp[3];
            acc[j] += A1[4] * wp[4]; acc[j] += A1[5] * wp[5];
            acc[j] += A1[6] * wp[6]; acc[j] += A1[7] * wp[7];
        }
#pragma unroll
        for (int t = 0; t < 8; t++) A1[t] = ap[(kk + 24 + t) * NPOS];
    }
    // tail: k = 496..511, no prefetch
    {
        const int kk = KDIM - 16;
#pragma unroll
        for (int j = 0; j < 2; j++) {
            const float* wp = wsBase + j * KDIM + kk;
            acc[j] += A0[0] * wp[0]; acc[j] += A0[1] * wp[1];
            acc[j] += A0[2] * wp[2]; acc[j] += A0[3] * wp[3];
            acc[j] += A0[4] * wp[4]; acc[j] += A0[5] * wp[5];
            acc[j] += A0[6] * wp[6]; acc[j] += A0[7] * wp[7];
        }
#pragma unroll
        for (int j = 0; j < 2; j++) {
            const float* wp = wsBase + j * KDIM + kk + 8;
            acc[j] += A1[0] * wp[0]; acc[j] += A1[1] * wp[1];
            acc[j] += A1[2] * wp[2]; acc[j] += A1[3] * wp[3];
            acc[j] += A1[4] * wp[4]; acc[j] += A1[5] * wp[5];
            acc[j] += A1[6] * wp[6]; acc[j] += A1[7] * wp[7];
        }
    }

    const int hw = hw0 + pos;
    if (isCls) {
        float2 rv = make_float2(acc[0] + bias[0], acc[1] + bias[1]);
        *(float2*)&clsRaw[hw * 400 + nTile * 8 + og * 2] = rv;   // 8B-aligned
    } else {
#pragma unroll
        for (int j = 0; j < 2; j++) {
            int o = (nTile - 50) * 8 + og * 2 + j;
            if (ok[j]) roRaw[hw * 25 + o] = acc[j] + bias[j];
        }
    }
}

// ---------------------------------------------------------------------------
// K2: per-box scores, argmax label, decode, outputs. BYTE-IDENTICAL to the
// R5-verified kernel (2000 blocks; inferred ~3-5 us from R14 phase-A scaling).
// ---------------------------------------------------------------------------
__global__ __launch_bounds__(256) void k_box(
    const float* __restrict__ clsRaw, const float* __restrict__ roRaw,
    float* __restrict__ out,          // d_out: [32000 bboxes][8000 score][8000 labels][8000 keep]
    float4* __restrict__ nmsBox, float* __restrict__ nmsArea,
    float2* __restrict__ sl)          // packed (score,label) for k_nms scan
{
    const int n = blockIdx.x * 4 + (threadIdx.x >> 6);   // box index 0..7999
    const int lane = threadIdx.x & 63;
    const int hw = n / 5, a = n % 5;

    const float sobj = sigf(roRaw[hw * 25 + a]);
    const float* cbase = clsRaw + hw * 400 + a * 80;

    const int l4 = (lane < 20) ? lane : 19;     // clamp for safe address
    float4 cs = *(const float4*)(cbase + l4 * 4);

    float s0 = sqrtf(sobj * sigf(cs.x));
    float s1 = sqrtf(sobj * sigf(cs.y));
    float s2 = sqrtf(sobj * sigf(cs.z));
    float s3 = sqrtf(sobj * sigf(cs.w));
    float v = s0; int bi = l4 * 4;
    if (s1 > v) { v = s1; bi = l4 * 4 + 1; }
    if (s2 > v) { v = s2; bi = l4 * 4 + 2; }
    if (s3 > v) { v = s3; bi = l4 * 4 + 3; }
    if (lane >= 20) { v = -1.0f; bi = 0x7FFFFFFF; }  // scores are always > 0

#pragma unroll
    for (int off = 32; off >= 1; off >>= 1) {
        float ov = __shfl_xor(v, off);
        int   oi = __shfl_xor(bi, off);
        if (ov > v || (ov == v && oi < bi)) { v = ov; bi = oi; }
    }

    if (lane == 0) {
        const float* rp = roRaw + hw * 25 + 5 + a * 4;
        float r0 = rp[0], r1 = rp[1], r2 = rp[2], r3 = rp[3];
        float gx = (float)(hw % FMPX), gy = (float)(hw / FMPX);
        float cx = (sigf(r0) + gx) * 32.0f;
        float cy = (sigf(r1) + gy) * 32.0f;
        float wv = expf(r2) * c_aw[a];
        float hv = expf(r3) * c_ah[a];
        float x1 = cx - wv * 0.5f, y1 = cy - hv * 0.5f;
        float x2 = cx + wv * 0.5f, y2 = cy + hv * 0.5f;

        out[n * 4 + 0] = x1; out[n * 4 + 1] = y1;
        out[n * 4 + 2] = x2; out[n * 4 + 3] = y2;
        out[32000 + n] = v;
        out[40000 + n] = (float)bi;
        out[48000 + n] = 0.0f;            // keep init (k_nms sets 1s later)
        sl[n] = make_float2(v, (float)bi);

        // b2: reinterpret x1y1x2y2 as cxcywh (faithful to the reference nms())
        float nx1 = x1 - x2 * 0.5f, ny1 = y1 - y2 * 0.5f;
        float nx2 = x1 + x2 * 0.5f, ny2 = y1 + y2 * 0.5f;
        nmsBox[n]  = make_float4(nx1, ny1, nx2, ny2);
        nmsArea[n] = (nx2 - nx1) * (ny2 - ny1);
    }
}

// ---------------------------------------------------------------------------
// K3: VERBATIM the R5-verified k_nms — the fastest measured variant (41.2 us).
// R7-R13 redesigns (wave-argmax, ballot-greedy, edge-matrix, packed keys) all
// lost to it: the 4-wave barrier-interleaved bitonic+greedy hides LDS latency
// via TLP better than any single-wave serial chain. Do not touch.
// ---------------------------------------------------------------------------
__global__ __launch_bounds__(256) void k_nms(
    const float2* __restrict__ sl,
    const float4* __restrict__ nmsBox, const float* __restrict__ nmsArea,
    float* __restrict__ keepOut)
{
    const int c = blockIdx.x;

    __shared__ float ss[CAP];
    __shared__ int   si[CAP];
    __shared__ float bx1[CAP], by1[CAP], bx2[CAP], by2[CAP], bar[CAP];
    __shared__ int   supp[CAP];
    __shared__ int   cnt;

    if (threadIdx.x == 0) cnt = 0;
    __syncthreads();

    for (int i = threadIdx.x; i < NBOX; i += 256) {
        float2 p = sl[i];
        if (p.x >= 0.3f && (int)p.y == c) {
            int q = atomicAdd(&cnt, 1);          // LDS atomic
            if (q < CAP) { ss[q] = p.x; si[q] = i; }
        }
    }
    __syncthreads();

    int m = cnt;
    if (m > CAP) m = CAP;

    // P = next pow2 >= m (min 2); pad with -inf sentinels.
    int P = 2;
    while (P < m) P <<= 1;
    for (int i = threadIdx.x; i < P; i += 256) {
        if (i >= m) { ss[i] = -INFINITY; si[i] = 0x7FFFFFFF; }
    }
    __syncthreads();

    for (int size = 2; size <= P; size <<= 1) {
        for (int stride = size >> 1; stride > 0; stride >>= 1) {
            for (int t = threadIdx.x; t < P / 2; t += 256) {
                int lo = 2 * stride * (t / stride) + (t % stride);
                int hi = lo + stride;
                bool desc = ((lo & size) == 0);
                float slo = ss[lo], shi = ss[hi];
                int   ilo = si[lo], ihi = si[hi];
                bool loBetter = (slo > shi) || (slo == shi && ilo < ihi);
                bool doSwap = desc ? !loBetter : loBetter;
                if (doSwap) { ss[lo] = shi; ss[hi] = slo; si[lo] = ihi; si[hi] = ilo; }
            }
            __syncthreads();
        }
    }

    for (int i = threadIdx.x; i < m; i += 256) {
        int n = si[i];
        float4 b = nmsBox[n];
        bx1[i] = b.x; by1[i] = b.y; bx2[i] = b.z; by2[i] = b.w;
        bar[i] = nmsArea[n];
        supp[i] = 0;
    }
    __syncthreads();

    for (int k = 0; k < m; k++) {
        if (!supp[k]) {
            float kx1 = bx1[k], ky1 = by1[k], kx2 = bx2[k], ky2 = by2[k], ka = bar[k];
            for (int j = k + 1 + threadIdx.x; j < m; j += 256) {
                float xx1 = fmaxf(kx1, bx1[j]);
                float yy1 = fmaxf(ky1, by1[j]);
                float xx2 = fminf(kx2, bx2[j]);
                float yy2 = fminf(ky2, by2[j]);
                float inter = fmaxf(1e-10f, xx2 - xx1) * fmaxf(1e-10f, yy2 - yy1);
                float iou = inter / ((ka + bar[j] - inter) + 1e-14f);
                if (iou > 0.5f) supp[j] = 1;
            }
        }
        __syncthreads();
    }

    for (int j = threadIdx.x; j < m; j += 256) {
        if (!supp[j]) keepOut[si[j]] = 1.0f;
    }
}

// ---------------------------------------------------------------------------
extern "C" void kernel_launch(void* const* d_in, const int* in_sizes, int n_in,
                              void* d_out, int out_size, void* d_ws, size_t ws_size,
                              hipStream_t stream) {
    const float* cls_feat = (const float*)d_in[0];
    const float* reg_feat = (const float*)d_in[1];
    const float* w_obj    = (const float*)d_in[2];
    const float* b_obj    = (const float*)d_in[3];
    const float* w_cls    = (const float*)d_in[4];
    const float* b_cls    = (const float*)d_in[5];
    const float* w_reg    = (const float*)d_in[6];
    const float* b_reg    = (const float*)d_in[7];

    float* out = (float*)d_out;
    float* ws  = (float*)d_ws;

    // workspace layout (floats) — IDENTICAL to the R5-proven layout, 2.944 MB
    float*  clsRaw    = ws;                       // 640000
    float*  roRaw     = ws + 640000;              // 40000
    float4* nmsBox    = (float4*)(ws + 680000);   // 32000 floats (16B-aligned offset)
    float*  nmsArea   = ws + 712000;              // 8000
    float2* sl        = (float2*)(ws + 720000);   // 16000 floats (8B-aligned)
    // total 736000 floats

    k_gemm<<<dim3(25, 54), 256, 0, stream>>>(cls_feat, reg_feat,
                                             w_obj, b_obj, w_cls, b_cls, w_reg, b_reg,
                                             clsRaw, roRaw);
    k_box<<<NBOX / 4, 256, 0, stream>>>(clsRaw, roRaw, out, nmsBox, nmsArea, sl);
    k_nms<<<NCLS, 256, 0, stream>>>(sl, nmsBox, nmsArea, out + 48000);
}